// Round 3
// baseline (754.078 us; speedup 1.0000x reference)
//
#include <hip/hip_runtime.h>
#include <hip/hip_bf16.h>

// Problem constants (fixed by the reference)
#define NTOT 100000
#define DIM  512
#define CB   4096
#define SSUP 50000
#define NQ   (NTOT - SSUP)

// 128x128-tile GEMM geometry (8-phase schedule, 2 blocks/CU)
#define MTILES 391            // ceil(50000/128); rows 50000..50047 are query rows, results discarded
#define MPAD   (MTILES * 128) // 50048
#define NTILES 32             // 4096/128
#define NWG    (MTILES * NTILES)   // 12512 = 8 * 1564
#define CPX    (NWG / 8)           // 1564 blocks per XCD chunk

typedef __bf16 bf16x8 __attribute__((ext_vector_type(8)));
typedef __bf16 bf16x4 __attribute__((ext_vector_type(4)));
typedef float  f32x4  __attribute__((ext_vector_type(4)));

// ---------------- ws layout, fast path (bytes) — identical to round-0 (known to fit) ----------------
// cbb   : CB*DIM*2        = 4,194,304   @ 0
// Xb    : MPAD*DIM*2      = 51,249,152  @ 4,194,304
// pv    : MPAD*32*4       = 6,406,144   @ 55,443,456
// pi    : MPAD*32*4       = 6,406,144   @ 61,849,600
// protoSum: 2048                        @ 68,255,744
// pcSum : 2048                          @ 68,257,792
// hist  : 16384                         @ 68,259,840
// top_idx: 200,000                      @ 68,276,224
#define OFF_CBBF   0
#define OFF_XB     4194304
#define OFF_PV     55443456
#define OFF_PI     61849600
#define OFF_PSUM   68255744
#define OFF_PCSUM  68257792
#define OFF_HIST   68259840
#define OFF_TIDX   68276224
#define WS_NEED    (68276224 + 200000)
#define ZERO_BYTES (2048 + 2048 + 16384)

// ---------------- ws layout, fallback (round-1) ----------------
#define F_OFF_PSUM   4194304
#define F_OFF_PCSUM  4196352
#define F_OFF_HIST   4198400
#define F_OFF_TIDX   4214784

// ---------------- async global->LDS helper ----------------
__device__ __forceinline__ void load_lds16(const void* g, void* l) {
    __builtin_amdgcn_global_load_lds(
        (const __attribute__((address_space(1))) void*)g,
        (__attribute__((address_space(3))) void*)l, 16, 0, 0);
}

// raw barrier (no implicit vmcnt(0) drain, unlike __syncthreads)
#define BARRIER() __builtin_amdgcn_s_barrier()
#define LGKM0()   do { asm volatile("s_waitcnt lgkmcnt(0)" ::: "memory"); \
                       __builtin_amdgcn_sched_barrier(0); } while (0)
#define VMC(N)    asm volatile("s_waitcnt vmcnt(" #N ")" ::: "memory")

// ---------------- fp32 -> bf16 convert (codebook) ----------------
__global__ void k_convert(const float* __restrict__ src, __bf16* __restrict__ dst) {
    int i = (blockIdx.x * 256 + threadIdx.x) * 4;
    float4 v = *(const float4*)(src + i);
    bf16x4 o;
    o[0] = (__bf16)v.x; o[1] = (__bf16)v.y; o[2] = (__bf16)v.z; o[3] = (__bf16)v.w;
    *(bf16x4*)(dst + i) = o;
}

// ---------------- fused X convert + support column-sum ----------------
// 782 blocks x 64 rows (50048 = 782*64 exact). Thread owns 8 fixed cols,
// 4 row-subgroups. Rows >= SSUP are converted (GEMM pad) but excluded from sum.
__global__ __launch_bounds__(256)
void k_conv_psum(const float* __restrict__ X, __bf16* __restrict__ Xb,
                 float* __restrict__ protoSum)
{
    __shared__ float red[4][512];
    const int tid  = threadIdx.x;
    const int c8   = (tid & 63) * 8;
    const int rsub = tid >> 6;
    const size_t rbase = (size_t)blockIdx.x * 64 + rsub;

    float acc[8];
    #pragma unroll
    for (int j = 0; j < 8; ++j) acc[j] = 0.f;

    for (int r = 0; r < 64; r += 4) {
        const size_t row = rbase + r;
        const float* p = X + row * DIM + c8;
        float4 v0 = *(const float4*)p;
        float4 v1 = *(const float4*)(p + 4);
        bf16x8 o;
        o[0] = (__bf16)v0.x; o[1] = (__bf16)v0.y; o[2] = (__bf16)v0.z; o[3] = (__bf16)v0.w;
        o[4] = (__bf16)v1.x; o[5] = (__bf16)v1.y; o[6] = (__bf16)v1.z; o[7] = (__bf16)v1.w;
        *(bf16x8*)(Xb + row * DIM + c8) = o;
        if (row < SSUP) {
            acc[0] += v0.x; acc[1] += v0.y; acc[2] += v0.z; acc[3] += v0.w;
            acc[4] += v1.x; acc[5] += v1.y; acc[6] += v1.z; acc[7] += v1.w;
        }
    }
    #pragma unroll
    for (int j = 0; j < 8; ++j) red[rsub][c8 + j] = acc[j];
    __syncthreads();
    if (rsub == 0) {
        #pragma unroll
        for (int j = 0; j < 8; ++j)
            atomicAdd(&protoSum[c8 + j],
                      red[0][c8 + j] + red[1][c8 + j] + red[2][c8 + j] + red[3][c8 + j]);
    }
}

// ---------------- 128^2 8-phase GEMM + fused per-tile argmax ----------------
// BM=BN=128, BK=64, 256 thr = 4 waves (2M x 2N). Per-wave output 64x64.
// LDS 64 KiB -> 2 independent blocks/CU (cross-block overlap, m114).
// buf0: A@0, B@16384 ; buf1: A@32768, B@49152. Operand = 128 rows x 128 B,
// half h = 64 rows @ +h*8192, linear row*128 within.
// T2 swizzle: 16B chunk c -> c ^ (row&7) on BOTH the pre-swizzled global
// source (linear LDS dest) and the ds_read offset (XOR involution).
// Ledger identical to the verified 8-phase template (2 loads per stage_half):
//  prologue 12 out, VMC(4); per-iter gates VMC(4) at ph4/ph8; VMC(0) once in epilogue.

__device__ __forceinline__ void stage_half(const __bf16* __restrict__ g, size_t grow0,
                                           int k0, char* ldsop, int half, int tid)
{
    char* dst = ldsop + half * 8192;
    #pragma unroll
    for (int i = 0; i < 2; ++i) {
        const int ck  = i * 256 + tid;   // 0..511, 16 B each; wave-linear dest
        const int row = ck >> 3;         // 0..63 within half
        const int sc  = (ck & 7) ^ (row & 7);
        load_lds16(g + (grow0 + (size_t)row) * DIM + k0 + sc * 8, dst + ck * 16);
    }
}

template<int BUFOFF, int MH>
__device__ __forceinline__ void ds_load_A(const char* aptr, int off0, int off1,
                                          bf16x8 (&a)[2][2])
{
    #pragma unroll
    for (int t = 0; t < 2; ++t) {
        const char* p = aptr + BUFOFF + MH * 4096 + t * 2048;
        a[t][0] = *(const bf16x8*)(p + off0);
        a[t][1] = *(const bf16x8*)(p + off1);
    }
}

template<int BUFOFF, int NH>
__device__ __forceinline__ void ds_load_B(const char* bptr, int off0, int off1,
                                          bf16x8 (&b)[2][2])
{
    #pragma unroll
    for (int n = 0; n < 2; ++n) {
        const char* p = bptr + BUFOFF + NH * 4096 + n * 2048;
        b[n][0] = *(const bf16x8*)(p + off0);
        b[n][1] = *(const bf16x8*)(p + off1);
    }
}

template<int MH, int NH>
__device__ __forceinline__ void mfma_quad(const bf16x8 (&a)[2][2], const bf16x8 (&b)[2][2],
                                          f32x4 (&acc)[4][4])
{
    __builtin_amdgcn_s_setprio(1);
    #pragma unroll
    for (int t = 0; t < 2; ++t)
        #pragma unroll
        for (int n = 0; n < 2; ++n)
            #pragma unroll
            for (int ks = 0; ks < 2; ++ks)
                acc[MH * 2 + t][NH * 2 + n] = __builtin_amdgcn_mfma_f32_16x16x32_bf16(
                    a[t][ks], b[n][ks], acc[MH * 2 + t][NH * 2 + n], 0, 0, 0);
    __builtin_amdgcn_s_setprio(0);
    __builtin_amdgcn_sched_barrier(0);
}

__global__ __launch_bounds__(256, 2)
void k_gemm128(const __bf16* __restrict__ Xb, const __bf16* __restrict__ cbb,
               float* __restrict__ pv, int* __restrict__ pi)
{
    __shared__ __align__(16) char lds[65536];

    const int tid  = threadIdx.x;
    const int lane = tid & 63;
    const int wid  = tid >> 6;            // 0..3
    const int wm   = wid >> 1;            // 0..1
    const int wn   = wid & 1;             // 0..1
    const int l15  = lane & 15;
    const int q    = lane >> 4;

    // XCD-aware bijective chunked swizzle: nwg = 12512 = 8 * 1564.
    // lin is nt-fastest; each XCD gets a contiguous chunk -> 32 consecutive
    // blocks share one 128-row A-panel (L2-resident) and cycle cbb (4 MB).
    const int lin = blockIdx.y * NTILES + blockIdx.x;
    const int swz = (lin & 7) * CPX + (lin >> 3);
    const int mt  = swz >> 5;             // 0..390
    const int nt  = swz & 31;             // 0..31
    const size_t r0  = (size_t)mt * 128;
    const size_t c0g = (size_t)nt * 128;

    // swizzled ds_read byte offsets (chunk = ks*4+q, row&7 == l15&7)
    const int off0 = l15 * 128 + ((q)     ^ (l15 & 7)) * 16;   // ks=0
    const int off1 = l15 * 128 + ((4 + q) ^ (l15 & 7)) * 16;   // ks=1
    const char* aptr = lds + wm * 8192;            // + wm*64 rows (A operand base)
    const char* bptr = lds + 16384 + wn * 8192;    // + wn*64 rows (B operand base)

    f32x4 acc[4][4];
    #pragma unroll
    for (int i = 0; i < 4; ++i)
        #pragma unroll
        for (int j = 0; j < 4; ++j)
            acc[i][j] = (f32x4){0.f, 0.f, 0.f, 0.f};

    bf16x8 a[2][2], b0[2][2], b1[2][2];

    // ---- prologue: tile0 full (buf0) + tile1 B-halves (buf1). 12 loads, keep 4 in flight.
    stage_half(Xb,  r0,       0,  lds + 0,     0, tid);
    stage_half(Xb,  r0 + 64,  0,  lds + 0,     1, tid);
    stage_half(cbb, c0g,      0,  lds + 16384, 0, tid);
    stage_half(cbb, c0g + 64, 0,  lds + 16384, 1, tid);
    stage_half(cbb, c0g,      64, lds + 49152, 0, tid);
    stage_half(cbb, c0g + 64, 64, lds + 49152, 1, tid);
    VMC(4);
    BARRIER();

    // ---- main loop: iteration processes tiles u=2it (buf0, ph1-4), u+1 (buf1, ph5-8).
    //  ph1: A.lo(u+1)->buf1  ph2: A.hi(u+1)->buf1  ph3: B.lo(u+2)->buf0
    //  ph4: B.hi(u+2)->buf0 +VMC(4)                ph5: A.lo(u+2)->buf0
    //  ph6: A.hi(u+2)->buf0  ph7: B.lo(u+3)->buf1  ph8: B.hi(u+3)->buf1 +VMC(4)
    #pragma unroll 1
    for (int it = 0; it < 3; ++it) {
        const int kA1 = (2 * it + 1) * 64;
        const int k2  = (2 * it + 2) * 64;
        const int kB3 = (2 * it + 3) * 64;
        // ph1: buf0 quad(0,0)
        ds_load_A<0, 0>(aptr, off0, off1, a);
        ds_load_B<0, 0>(bptr, off0, off1, b0);
        stage_half(Xb, r0, kA1, lds + 32768, 0, tid);
        BARRIER(); LGKM0();
        mfma_quad<0, 0>(a, b0, acc);
        BARRIER();
        // ph2: buf0 quad(0,1)
        ds_load_B<0, 1>(bptr, off0, off1, b1);
        stage_half(Xb, r0 + 64, kA1, lds + 32768, 1, tid);
        BARRIER(); LGKM0();
        mfma_quad<0, 1>(a, b1, acc);
        BARRIER();
        // ph3: buf0 quad(1,1)
        ds_load_A<0, 1>(aptr, off0, off1, a);
        stage_half(cbb, c0g, k2, lds + 16384, 0, tid);
        BARRIER(); LGKM0();
        mfma_quad<1, 1>(a, b1, acc);
        BARRIER();
        // ph4: buf0 quad(1,0); tile u+1 guaranteed landed after VMC(4)+barrier
        stage_half(cbb, c0g + 64, k2, lds + 16384, 1, tid);
        VMC(4);
        BARRIER();
        mfma_quad<1, 0>(a, b0, acc);
        BARRIER();
        // ph5: buf1 quad(0,0)
        ds_load_A<32768, 0>(aptr, off0, off1, a);
        ds_load_B<32768, 0>(bptr, off0, off1, b0);
        stage_half(Xb, r0, k2, lds + 0, 0, tid);
        BARRIER(); LGKM0();
        mfma_quad<0, 0>(a, b0, acc);
        BARRIER();
        // ph6: buf1 quad(0,1)
        ds_load_B<32768, 1>(bptr, off0, off1, b1);
        stage_half(Xb, r0 + 64, k2, lds + 0, 1, tid);
        BARRIER(); LGKM0();
        mfma_quad<0, 1>(a, b1, acc);
        BARRIER();
        // ph7: buf1 quad(1,1)
        ds_load_A<32768, 1>(aptr, off0, off1, a);
        stage_half(cbb, c0g, kB3, lds + 49152, 0, tid);
        BARRIER(); LGKM0();
        mfma_quad<1, 1>(a, b1, acc);
        BARRIER();
        // ph8: buf1 quad(1,0); tile u+2 guaranteed landed
        stage_half(cbb, c0g + 64, kB3, lds + 49152, 1, tid);
        VMC(4);
        BARRIER();
        mfma_quad<1, 0>(a, b0, acc);
        BARRIER();
    }

    // ---- epilogue: tiles 6 (buf0) and 7 (buf1); drain to vmcnt(0) once.
    {
        const int k7 = 7 * 64;
        ds_load_A<0, 0>(aptr, off0, off1, a);
        ds_load_B<0, 0>(bptr, off0, off1, b0);
        stage_half(Xb, r0, k7, lds + 32768, 0, tid);
        BARRIER(); LGKM0();
        mfma_quad<0, 0>(a, b0, acc);
        BARRIER();

        ds_load_B<0, 1>(bptr, off0, off1, b1);
        stage_half(Xb, r0 + 64, k7, lds + 32768, 1, tid);
        BARRIER(); LGKM0();
        mfma_quad<0, 1>(a, b1, acc);
        BARRIER();

        ds_load_A<0, 1>(aptr, off0, off1, a);
        BARRIER(); LGKM0();
        mfma_quad<1, 1>(a, b1, acc);
        BARRIER();

        VMC(0);
        BARRIER();
        mfma_quad<1, 0>(a, b0, acc);
        BARRIER();

        ds_load_A<32768, 0>(aptr, off0, off1, a);
        ds_load_B<32768, 0>(bptr, off0, off1, b0);
        BARRIER(); LGKM0();
        mfma_quad<0, 0>(a, b0, acc);
        BARRIER();

        ds_load_B<32768, 1>(bptr, off0, off1, b1);
        BARRIER(); LGKM0();
        mfma_quad<0, 1>(a, b1, acc);
        BARRIER();

        ds_load_A<32768, 1>(aptr, off0, off1, a);
        BARRIER(); LGKM0();
        mfma_quad<1, 1>(a, b1, acc);
        BARRIER();

        mfma_quad<1, 0>(a, b0, acc);
    }

    // ---- fused argmax over the block's 128 cols.
    // C/D: col = c0g + wn*64 + fn*16 + l15 ; row = r0 + wm*64 + fm*16 + q*4 + reg
    __shared__ float sv[128][2];
    __shared__ int   si[128][2];
    #pragma unroll
    for (int fm = 0; fm < 4; ++fm) {
        #pragma unroll
        for (int reg = 0; reg < 4; ++reg) {
            float v = -3.0e38f; int idx = 0;
            #pragma unroll
            for (int fn = 0; fn < 4; ++fn) {
                float x = acc[fm][fn][reg];
                int   c = (int)c0g + wn * 64 + fn * 16 + l15;
                if (x > v) { v = x; idx = c; }
            }
            #pragma unroll
            for (int off = 1; off < 16; off <<= 1) {
                float ov = __shfl_xor(v, off, 64);
                int   oi = __shfl_xor(idx, off, 64);
                if (ov > v) { v = ov; idx = oi; }
            }
            if (l15 == 0) {
                int rl = wm * 64 + fm * 16 + q * 4 + reg;
                sv[rl][wn] = v;
                si[rl][wn] = idx;
            }
        }
    }
    __syncthreads();
    if (tid < 128) {
        float v0 = sv[tid][0], v1 = sv[tid][1];
        size_t r = r0 + tid;
        pv[r * 32 + nt] = fmaxf(v0, v1);
        pi[r * 32 + nt] = (v1 > v0) ? si[tid][1] : si[tid][0];
    }
}

// ---------------- phase-2: reduce 32 tile-partials per row ----------------
__global__ void k_argmax_reduce(const float* __restrict__ pv, const int* __restrict__ pi,
                                int* __restrict__ top_idx) {
    int r = blockIdx.x * 256 + threadIdx.x;
    if (r >= SSUP) return;
    float v = -3.0e38f; int idx = 0;
    #pragma unroll 8
    for (int j = 0; j < 32; ++j) {
        float x = pv[(size_t)r * 32 + j];
        if (x > v) { v = x; idx = pi[(size_t)r * 32 + j]; }
    }
    top_idx[r] = idx;
}

// ---------------- column sums of support (fallback path) ----------------
__global__ void k_proto_sum(const float* __restrict__ X, float* __restrict__ protoSum) {
    const int d = threadIdx.x;              // 512 threads
    const int r0 = blockIdx.x * 500;        // 100 blocks x 500 rows
    float acc = 0.f;
    for (int r = r0; r < r0 + 500; ++r)
        acc += X[(size_t)r * DIM + d];
    atomicAdd(&protoSum[d], acc);
}

// ---------------- fallback GEMM (round-1, known-correct) ----------------
__global__ __launch_bounds__(256, 2)
void k_gemm_argmax(const float* __restrict__ X, const __bf16* __restrict__ cbb,
                   int* __restrict__ top_idx)
{
    __shared__ float redv[64][2];
    __shared__ int   redi[64][2];

    const int tid  = threadIdx.x;
    const int wave = tid >> 6;
    const int lane = tid & 63;
    const int wm   = wave >> 1;
    const int wn   = wave & 1;
    const int l15  = lane & 15;
    const int q    = lane >> 4;
    const int r0   = blockIdx.x * 64;

    bf16x8 aflat[2][16];
    #pragma unroll
    for (int tm = 0; tm < 2; ++tm) {
        const int r = r0 + wm * 32 + tm * 16 + l15;
        const bool valid = (r < SSUP);
        const float* xr = X + (size_t)r * DIM + q * 8;
        #pragma unroll
        for (int kt = 0; kt < 16; ++kt) {
            float4 v0, v1;
            if (valid) {
                v0 = *(const float4*)(xr + kt * 32);
                v1 = *(const float4*)(xr + kt * 32 + 4);
            } else {
                v0 = make_float4(0.f, 0.f, 0.f, 0.f);
                v1 = v0;
            }
            bf16x8 f;
            f[0] = (__bf16)v0.x; f[1] = (__bf16)v0.y; f[2] = (__bf16)v0.z; f[3] = (__bf16)v0.w;
            f[4] = (__bf16)v1.x; f[5] = (__bf16)v1.y; f[6] = (__bf16)v1.z; f[7] = (__bf16)v1.w;
            aflat[tm][kt] = f;
        }
    }

    float mx[8];
    int   mi[8];
    #pragma unroll
    for (int i = 0; i < 8; ++i) { mx[i] = -3.0e38f; mi[i] = 0; }
    const f32x4 zero4 = {0.f, 0.f, 0.f, 0.f};

    for (int ct = 0; ct < 32; ++ct) {
        const int c0 = ct * 128 + wn * 64;
        const __bf16* bptr[4];
        #pragma unroll
        for (int tn = 0; tn < 4; ++tn)
            bptr[tn] = cbb + (size_t)(c0 + tn * 16 + l15) * DIM + q * 8;

        f32x4 acc[2][4];
        #pragma unroll
        for (int i = 0; i < 2; ++i)
            #pragma unroll
            for (int j = 0; j < 4; ++j)
                acc[i][j] = zero4;

        #pragma unroll
        for (int kt = 0; kt < 16; ++kt) {
            bf16x8 b[4];
            #pragma unroll
            for (int tn = 0; tn < 4; ++tn)
                b[tn] = *(const bf16x8*)(bptr[tn] + kt * 32);
            #pragma unroll
            for (int tm = 0; tm < 2; ++tm)
                #pragma unroll
                for (int tn = 0; tn < 4; ++tn)
                    acc[tm][tn] = __builtin_amdgcn_mfma_f32_16x16x32_bf16(
                        aflat[tm][kt], b[tn], acc[tm][tn], 0, 0, 0);
        }
        #pragma unroll
        for (int tm = 0; tm < 2; ++tm)
            #pragma unroll
            for (int tn = 0; tn < 4; ++tn)
                #pragma unroll
                for (int reg = 0; reg < 4; ++reg) {
                    float v = acc[tm][tn][reg];
                    int slot = tm * 4 + reg;
                    int col  = c0 + tn * 16 + l15;
                    if (v > mx[slot]) { mx[slot] = v; mi[slot] = col; }
                }
    }

    #pragma unroll
    for (int slot = 0; slot < 8; ++slot) {
        float v  = mx[slot];
        int  idx = mi[slot];
        #pragma unroll
        for (int off = 1; off < 16; off <<= 1) {
            float ov = __shfl_xor(v, off, 64);
            int   oi = __shfl_xor(idx, off, 64);
            if (ov > v) { v = ov; idx = oi; }
        }
        if (l15 == 0) {
            int rowl = wm * 32 + (slot >> 2) * 16 + q * 4 + (slot & 3);
            redv[rowl][wn] = v;
            redi[rowl][wn] = idx;
        }
    }
    __syncthreads();
    if (tid < 64) {
        int r = r0 + tid;
        if (r < SSUP) {
            float v0 = redv[tid][0], v1 = redv[tid][1];
            top_idx[r] = (v1 > v0) ? redi[tid][1] : redi[tid][0];
        }
    }
}

// ---------------- histogram of top_idx ----------------
__global__ void k_hist(const int* __restrict__ top_idx, int* __restrict__ hist) {
    __shared__ int lh[CB];
    for (int i = threadIdx.x; i < CB; i += blockDim.x) lh[i] = 0;
    __syncthreads();
    for (int i = blockIdx.x * blockDim.x + threadIdx.x; i < SSUP; i += gridDim.x * blockDim.x)
        atomicAdd(&lh[top_idx[i]], 1);
    __syncthreads();
    for (int i = threadIdx.x; i < CB; i += blockDim.x) {
        int v = lh[i];
        if (v) atomicAdd(&hist[i], v);
    }
}

// ---------------- weighted codebook sum (proto_code * S) ----------------
__global__ void k_proto_code(const float* __restrict__ cb, const int* __restrict__ hist,
                             float* __restrict__ pcSum) {
    const int d  = threadIdx.x;          // 512 threads
    const int c0 = blockIdx.x * 64;
    float acc = 0.f;
    for (int c = c0; c < c0 + 64; ++c) {
        float w = (float)hist[c];
        if (w != 0.f) acc += w * cb[(size_t)c * DIM + d];
    }
    atomicAdd(&pcSum[d], acc);
}

// ---------------- query scores ----------------
__global__ void k_query(const float* __restrict__ X, const float* __restrict__ protoSum,
                        const float* __restrict__ pcSum, float* __restrict__ out) {
    const int lane   = threadIdx.x & 63;
    const int waveId = (blockIdx.x * blockDim.x + threadIdx.x) >> 6;
    const int nwaves = (gridDim.x * blockDim.x) >> 6;
    const float invS = 1.0f / (float)SSUP;

    for (int r = waveId; r < NQ; r += nwaves) {
        const float* xr = X + (size_t)(SSUP + r) * DIM;
        float s1 = 0.f, s2 = 0.f;
        #pragma unroll
        for (int i = 0; i < 2; ++i) {
            int dd = lane * 4 + i * 256;
            float4 xq = *(const float4*)(xr + dd);
            float4 p  = *(const float4*)(protoSum + dd);
            float4 pc = *(const float4*)(pcSum + dd);
            float d0, d1, d2, d3;
            d0 = xq.x - p.x * invS; d1 = xq.y - p.y * invS;
            d2 = xq.z - p.z * invS; d3 = xq.w - p.w * invS;
            s1 += d0 * d0 + d1 * d1 + d2 * d2 + d3 * d3;
            d0 = xq.x - pc.x * invS; d1 = xq.y - pc.y * invS;
            d2 = xq.z - pc.z * invS; d3 = xq.w - pc.w * invS;
            s2 += d0 * d0 + d1 * d1 + d2 * d2 + d3 * d3;
        }
        #pragma unroll
        for (int off = 32; off > 0; off >>= 1) {
            s1 += __shfl_xor(s1, off, 64);
            s2 += __shfl_xor(s2, off, 64);
        }
        if (lane == 0)
            out[r] = 0.5f * (sqrtf(s1) + sqrtf(s2));
    }
}

extern "C" void kernel_launch(void* const* d_in, const int* in_sizes, int n_in,
                              void* d_out, int out_size, void* d_ws, size_t ws_size,
                              hipStream_t stream) {
    const float* X  = (const float*)d_in[0];
    const float* cb = (const float*)d_in[1];
    float* out = (float*)d_out;
    char* ws = (char*)d_ws;

    __bf16* cbb = (__bf16*)(ws + OFF_CBBF);

    if (ws_size >= (size_t)WS_NEED) {
        // ---- fast path: 128^2 8-phase tiled GEMM, 2 blocks/CU
        __bf16* Xb       = (__bf16*)(ws + OFF_XB);
        float*  pv       = (float*)(ws + OFF_PV);
        int*    pi       = (int*)(ws + OFF_PI);
        float*  protoSum = (float*)(ws + OFF_PSUM);
        float*  pcSum    = (float*)(ws + OFF_PCSUM);
        int*    hist     = (int*)(ws + OFF_HIST);
        int*    top_idx  = (int*)(ws + OFF_TIDX);

        hipMemsetAsync(ws + OFF_PSUM, 0, ZERO_BYTES, stream);

        k_convert<<<(CB * DIM) / 1024, 256, 0, stream>>>(cb, cbb);
        k_conv_psum<<<MPAD / 64, 256, 0, stream>>>(X, Xb, protoSum);

        dim3 grid(NTILES, MTILES);
        k_gemm128<<<grid, 256, 0, stream>>>(Xb, cbb, pv, pi);

        k_argmax_reduce<<<(SSUP + 255) / 256, 256, 0, stream>>>(pv, pi, top_idx);
        k_hist<<<64, 256, 0, stream>>>(top_idx, hist);
        k_proto_code<<<CB / 64, 512, 0, stream>>>(cb, hist, pcSum);
        k_query<<<1024, 256, 0, stream>>>(X, protoSum, pcSum, out);
    } else {
        // ---- fallback: round-1 path (needs only ~4.4 MB)
        float*  protoSum = (float*)(ws + F_OFF_PSUM);
        float*  pcSum    = (float*)(ws + F_OFF_PCSUM);
        int*    hist     = (int*)(ws + F_OFF_HIST);
        int*    top_idx  = (int*)(ws + F_OFF_TIDX);

        hipMemsetAsync(ws + F_OFF_PSUM, 0, ZERO_BYTES, stream);

        k_convert<<<(CB * DIM) / 1024, 256, 0, stream>>>(cb, cbb);
        k_proto_sum<<<100, 512, 0, stream>>>(X, protoSum);
        k_gemm_argmax<<<(SSUP + 63) / 64, 256, 0, stream>>>(X, cbb, top_idx);
        k_hist<<<64, 256, 0, stream>>>(top_idx, hist);
        k_proto_code<<<CB / 64, 512, 0, stream>>>(cb, hist, pcSum);
        k_query<<<1024, 256, 0, stream>>>(X, protoSum, pcSum, out);
    }
}

// Round 4
// 681.319 us; speedup vs baseline: 1.1068x; 1.1068x over previous
//
#include <hip/hip_runtime.h>
#include <hip/hip_bf16.h>

// Problem constants (fixed by the reference)
#define NTOT 100000
#define DIM  512
#define CB   4096
#define SSUP 50000
#define NQ   (NTOT - SSUP)

// 128x128-tile GEMM geometry (1 compute step per BK=64 K-tile, 2 blocks/CU)
#define MTILES 391            // ceil(50000/128); rows 50000..50047 are query rows, results discarded
#define MPAD   (MTILES * 128) // 50048
#define NTILES 32             // 4096/128
#define NWG    (MTILES * NTILES)   // 12512 = 8 * 1564
#define CPX    (NWG / 8)           // 1564 blocks per XCD chunk

typedef __bf16 bf16x8 __attribute__((ext_vector_type(8)));
typedef __bf16 bf16x4 __attribute__((ext_vector_type(4)));
typedef float  f32x4  __attribute__((ext_vector_type(4)));

// ---------------- ws layout, fast path (bytes) ----------------
#define OFF_CBBF   0
#define OFF_XB     4194304
#define OFF_PV     55443456
#define OFF_PI     61849600
#define OFF_PSUM   68255744
#define OFF_PCSUM  68257792
#define OFF_HIST   68259840
#define OFF_TIDX   68276224
#define WS_NEED    (68276224 + 200000)
#define ZERO_BYTES (2048 + 2048 + 16384)

// ---------------- ws layout, fallback (round-1) ----------------
#define F_OFF_PSUM   4194304
#define F_OFF_PCSUM  4196352
#define F_OFF_HIST   4198400
#define F_OFF_TIDX   4214784

// ---------------- async global->LDS helper ----------------
__device__ __forceinline__ void load_lds16(const void* g, void* l) {
    __builtin_amdgcn_global_load_lds(
        (const __attribute__((address_space(1))) void*)g,
        (__attribute__((address_space(3))) void*)l, 16, 0, 0);
}

// raw barrier (no implicit vmcnt(0) drain, unlike __syncthreads)
#define BARRIER() __builtin_amdgcn_s_barrier()
#define VMC(N)    asm volatile("s_waitcnt vmcnt(" #N ")" ::: "memory")

// ---------------- fp32 -> bf16 convert (codebook) ----------------
__global__ void k_convert(const float* __restrict__ src, __bf16* __restrict__ dst) {
    int i = (blockIdx.x * 256 + threadIdx.x) * 4;
    float4 v = *(const float4*)(src + i);
    bf16x4 o;
    o[0] = (__bf16)v.x; o[1] = (__bf16)v.y; o[2] = (__bf16)v.z; o[3] = (__bf16)v.w;
    *(bf16x4*)(dst + i) = o;
}

// ---------------- fused X convert + support column-sum ----------------
// 391 blocks x 128 rows. Thread owns 8 fixed cols, 4 row-subgroups.
// Rows >= SSUP are converted (GEMM pad) but excluded from the sum.
__global__ __launch_bounds__(256)
void k_conv_psum(const float* __restrict__ X, __bf16* __restrict__ Xb,
                 float* __restrict__ protoSum)
{
    __shared__ float red[4][512];
    const int tid  = threadIdx.x;
    const int c8   = (tid & 63) * 8;
    const int rsub = tid >> 6;
    const size_t rbase = (size_t)blockIdx.x * 128 + rsub;

    float acc[8];
    #pragma unroll
    for (int j = 0; j < 8; ++j) acc[j] = 0.f;

    for (int r = 0; r < 128; r += 4) {
        const size_t row = rbase + r;
        const float* p = X + row * DIM + c8;
        float4 v0 = *(const float4*)p;
        float4 v1 = *(const float4*)(p + 4);
        bf16x8 o;
        o[0] = (__bf16)v0.x; o[1] = (__bf16)v0.y; o[2] = (__bf16)v0.z; o[3] = (__bf16)v0.w;
        o[4] = (__bf16)v1.x; o[5] = (__bf16)v1.y; o[6] = (__bf16)v1.z; o[7] = (__bf16)v1.w;
        *(bf16x8*)(Xb + row * DIM + c8) = o;
        if (row < SSUP) {
            acc[0] += v0.x; acc[1] += v0.y; acc[2] += v0.z; acc[3] += v0.w;
            acc[4] += v1.x; acc[5] += v1.y; acc[6] += v1.z; acc[7] += v1.w;
        }
    }
    #pragma unroll
    for (int j = 0; j < 8; ++j) red[rsub][c8 + j] = acc[j];
    __syncthreads();
    if (rsub == 0) {
        #pragma unroll
        for (int j = 0; j < 8; ++j)
            atomicAdd(&protoSum[c8 + j],
                      red[0][c8 + j] + red[1][c8 + j] + red[2][c8 + j] + red[3][c8 + j]);
    }
}

// ---------------- 128^2 GEMM, 1 compute step per BK=64 tile ----------------
// 256 thr = 4 waves (2M x 2N), wave-tile 64x64. LDS dbuf 2x32 KB -> 2 blocks/CU.
// Operand tile = 128 rows x 128 B; half at +8192; linear row*128 within.
// T2 swizzle (verified round-3): 16B chunk c -> c ^ (row&7) on BOTH the
// pre-swizzled global source (linear LDS dest) and the ds_read offset.
// Schedule per K-tile: {16 plain ds_reads + 32 MFMA (compiler-managed lgkm);
// BARRIER; STAGE(t+2, 8 loads); vmcnt(8); BARRIER}. Counted vmcnt, never 0
// in the main loop. 15 barriers/block total.

template<int MH, int NH>
__device__ __forceinline__ void mfma_quad_dummy() {}  // (placeholder removed)

__global__ __launch_bounds__(256, 2)
void k_gemm128(const __bf16* __restrict__ Xb, const __bf16* __restrict__ cbb,
               float* __restrict__ pv, int* __restrict__ pi)
{
    __shared__ __align__(16) char lds[65536];
    __shared__ float sv[128][2];
    __shared__ int   si[128][2];

    const int tid  = threadIdx.x;
    const int lane = tid & 63;
    const int wid  = tid >> 6;            // 0..3
    const int wm   = wid >> 1;            // 0..1
    const int wn   = wid & 1;             // 0..1
    const int l15  = lane & 15;
    const int q    = lane >> 4;

    // XCD-aware bijective chunked swizzle (verified round-3): nwg = 12512 = 8*1564.
    const int lin = blockIdx.y * NTILES + blockIdx.x;
    const int swz = (lin & 7) * CPX + (lin >> 3);
    const int mt  = swz >> 5;             // 0..390
    const int nt  = swz & 31;             // 0..31
    const size_t r0  = (size_t)mt * 128;
    const size_t c0g = (size_t)nt * 128;

    // swizzled ds_read byte offsets (chunk = ks*4+q, row&7 == l15&7)
    const int off0 = l15 * 128 + ((q)     ^ (l15 & 7)) * 16;   // ks=0
    const int off1 = l15 * 128 + ((4 + q) ^ (l15 & 7)) * 16;   // ks=1

    // per-thread staging setup (2 chunks per 64-row half; verified round-3 mapping)
    const int ck0 = tid, ck1 = 256 + tid;
    const int rw0 = ck0 >> 3, rw1 = ck1 >> 3;                  // 0..63
    const int sc0 = (ck0 & 7) ^ (rw0 & 7);
    const int sc1 = (ck1 & 7) ^ (rw1 & 7);
    const __bf16* pA0 = Xb  + (r0  + rw0) * DIM + sc0 * 8;
    const __bf16* pA1 = Xb  + (r0  + rw1) * DIM + sc1 * 8;
    const __bf16* pB0 = cbb + (c0g + rw0) * DIM + sc0 * 8;
    const __bf16* pB1 = cbb + (c0g + rw1) * DIM + sc1 * 8;
    const int d0 = ck0 * 16, d1 = ck1 * 16;
    const size_t HROW = (size_t)64 * DIM;   // 64-row half advance in source

    f32x4 acc[4][4];
    #pragma unroll
    for (int i = 0; i < 4; ++i)
        #pragma unroll
        for (int j = 0; j < 4; ++j)
            acc[i][j] = (f32x4){0.f, 0.f, 0.f, 0.f};

    // STAGE: full 32 KB K-tile (A lo/hi + B lo/hi), 8 loads/thread.
    auto STAGE = [&](int bufo, int kt) {
        const int ko = kt * 64;
        char* lb = lds + bufo;
        load_lds16(pA0 + ko,        lb + d0);
        load_lds16(pA1 + ko,        lb + d1);
        load_lds16(pA0 + HROW + ko, lb + 8192 + d0);
        load_lds16(pA1 + HROW + ko, lb + 8192 + d1);
        load_lds16(pB0 + ko,        lb + 16384 + d0);
        load_lds16(pB1 + ko,        lb + 16384 + d1);
        load_lds16(pB0 + HROW + ko, lb + 24576 + d0);
        load_lds16(pB1 + HROW + ko, lb + 24576 + d1);
    };

    // COMPUTE: 16 plain ds_reads + 32 MFMA; compiler inserts fine-grained lgkmcnt.
    auto COMPUTE = [&](int bufo) {
        const char* ap = lds + bufo + wm * 8192;
        const char* bp = lds + bufo + 16384 + wn * 8192;
        bf16x8 a[4][2], b[4][2];
        #pragma unroll
        for (int m = 0; m < 4; ++m) {
            a[m][0] = *(const bf16x8*)(ap + m * 2048 + off0);
            a[m][1] = *(const bf16x8*)(ap + m * 2048 + off1);
        }
        #pragma unroll
        for (int n = 0; n < 4; ++n) {
            b[n][0] = *(const bf16x8*)(bp + n * 2048 + off0);
            b[n][1] = *(const bf16x8*)(bp + n * 2048 + off1);
        }
        __builtin_amdgcn_s_setprio(1);
        #pragma unroll
        for (int m = 0; m < 4; ++m)
            #pragma unroll
            for (int n = 0; n < 4; ++n)
                #pragma unroll
                for (int ks = 0; ks < 2; ++ks)
                    acc[m][n] = __builtin_amdgcn_mfma_f32_16x16x32_bf16(
                        a[m][ks], b[n][ks], acc[m][n], 0, 0, 0);
        __builtin_amdgcn_s_setprio(0);
    };

    // ---- prologue: tiles 0 (buf0) and 1 (buf1); gate tile 0. 16 out -> 8.
    STAGE(0, 0);
    STAGE(32768, 1);
    VMC(8);
    BARRIER();

    // ---- main: 3 iterations cover tiles 0..5, staging 2..7.
    // ledger: enter iter with 8 outstanding (next tile); after STAGE 16; VMC(8)
    // retires the 8 oldest -> next buffer ready; never drains to 0.
    #pragma unroll
    for (int t = 0; t < 6; t += 2) {
        COMPUTE(0);
        BARRIER();
        STAGE(0, t + 2);
        VMC(8);
        BARRIER();
        COMPUTE(32768);
        BARRIER();
        STAGE(32768, t + 3);
        VMC(8);
        BARRIER();
    }

    // ---- epilogue: tiles 6 (buf0) and 7 (buf1); single drain to 0.
    COMPUTE(0);
    BARRIER();
    VMC(0);
    BARRIER();
    COMPUTE(32768);

    // ---- fused argmax over the block's 128 cols (verified round-0/3 epilogue).
    // C/D: col = c0g + wn*64 + fn*16 + l15 ; row = r0 + wm*64 + fm*16 + q*4 + reg
    #pragma unroll
    for (int fm = 0; fm < 4; ++fm) {
        #pragma unroll
        for (int reg = 0; reg < 4; ++reg) {
            float v = -3.0e38f; int idx = 0;
            #pragma unroll
            for (int fn = 0; fn < 4; ++fn) {
                float x = acc[fm][fn][reg];
                int   c = (int)c0g + wn * 64 + fn * 16 + l15;
                if (x > v) { v = x; idx = c; }
            }
            #pragma unroll
            for (int off = 1; off < 16; off <<= 1) {
                float ov = __shfl_xor(v, off, 64);
                int   oi = __shfl_xor(idx, off, 64);
                if (ov > v) { v = ov; idx = oi; }
            }
            if (l15 == 0) {
                int rl = wm * 64 + fm * 16 + q * 4 + reg;
                sv[rl][wn] = v;
                si[rl][wn] = idx;
            }
        }
    }
    __syncthreads();
    if (tid < 128) {
        float v0 = sv[tid][0], v1 = sv[tid][1];
        size_t r = r0 + tid;
        pv[r * 32 + nt] = fmaxf(v0, v1);
        pi[r * 32 + nt] = (v1 > v0) ? si[tid][1] : si[tid][0];
    }
}

// ---------------- fused phase-2: per-row argmax-reduce + histogram ----------------
// 196 blocks x 256 thr; thread owns one row; block-local LDS hist then global atomics.
__global__ __launch_bounds__(256)
void k_reduce_hist(const float* __restrict__ pv, const int* __restrict__ pi,
                   int* __restrict__ hist) {
    __shared__ int lh[CB];
    const int tid = threadIdx.x;
    for (int i = tid; i < CB; i += 256) lh[i] = 0;
    __syncthreads();
    const int r = blockIdx.x * 256 + tid;
    if (r < SSUP) {
        float v = -3.0e38f; int idx = 0;
        #pragma unroll 8
        for (int j = 0; j < 32; ++j) {
            float x = pv[(size_t)r * 32 + j];
            if (x > v) { v = x; idx = pi[(size_t)r * 32 + j]; }
        }
        atomicAdd(&lh[idx], 1);
    }
    __syncthreads();
    for (int i = tid; i < CB; i += 256) {
        int v = lh[i];
        if (v) atomicAdd(&hist[i], v);
    }
}

// ---------------- column sums of support (fallback path) ----------------
__global__ void k_proto_sum(const float* __restrict__ X, float* __restrict__ protoSum) {
    const int d = threadIdx.x;              // 512 threads
    const int r0 = blockIdx.x * 500;        // 100 blocks x 500 rows
    float acc = 0.f;
    for (int r = r0; r < r0 + 500; ++r)
        acc += X[(size_t)r * DIM + d];
    atomicAdd(&protoSum[d], acc);
}

// ---------------- fallback GEMM (round-1, known-correct) ----------------
__global__ __launch_bounds__(256, 2)
void k_gemm_argmax(const float* __restrict__ X, const __bf16* __restrict__ cbb,
                   int* __restrict__ top_idx)
{
    __shared__ float redv[64][2];
    __shared__ int   redi[64][2];

    const int tid  = threadIdx.x;
    const int wave = tid >> 6;
    const int lane = tid & 63;
    const int wm   = wave >> 1;
    const int wn   = wave & 1;
    const int l15  = lane & 15;
    const int q    = lane >> 4;
    const int r0   = blockIdx.x * 64;

    bf16x8 aflat[2][16];
    #pragma unroll
    for (int tm = 0; tm < 2; ++tm) {
        const int r = r0 + wm * 32 + tm * 16 + l15;
        const bool valid = (r < SSUP);
        const float* xr = X + (size_t)r * DIM + q * 8;
        #pragma unroll
        for (int kt = 0; kt < 16; ++kt) {
            float4 v0, v1;
            if (valid) {
                v0 = *(const float4*)(xr + kt * 32);
                v1 = *(const float4*)(xr + kt * 32 + 4);
            } else {
                v0 = make_float4(0.f, 0.f, 0.f, 0.f);
                v1 = v0;
            }
            bf16x8 f;
            f[0] = (__bf16)v0.x; f[1] = (__bf16)v0.y; f[2] = (__bf16)v0.z; f[3] = (__bf16)v0.w;
            f[4] = (__bf16)v1.x; f[5] = (__bf16)v1.y; f[6] = (__bf16)v1.z; f[7] = (__bf16)v1.w;
            aflat[tm][kt] = f;
        }
    }

    float mx[8];
    int   mi[8];
    #pragma unroll
    for (int i = 0; i < 8; ++i) { mx[i] = -3.0e38f; mi[i] = 0; }
    const f32x4 zero4 = {0.f, 0.f, 0.f, 0.f};

    for (int ct = 0; ct < 32; ++ct) {
        const int c0 = ct * 128 + wn * 64;
        const __bf16* bptr[4];
        #pragma unroll
        for (int tn = 0; tn < 4; ++tn)
            bptr[tn] = cbb + (size_t)(c0 + tn * 16 + l15) * DIM + q * 8;

        f32x4 acc[2][4];
        #pragma unroll
        for (int i = 0; i < 2; ++i)
            #pragma unroll
            for (int j = 0; j < 4; ++j)
                acc[i][j] = zero4;

        #pragma unroll
        for (int kt = 0; kt < 16; ++kt) {
            bf16x8 b[4];
            #pragma unroll
            for (int tn = 0; tn < 4; ++tn)
                b[tn] = *(const bf16x8*)(bptr[tn] + kt * 32);
            #pragma unroll
            for (int tm = 0; tm < 2; ++tm)
                #pragma unroll
                for (int tn = 0; tn < 4; ++tn)
                    acc[tm][tn] = __builtin_amdgcn_mfma_f32_16x16x32_bf16(
                        aflat[tm][kt], b[tn], acc[tm][tn], 0, 0, 0);
        }
        #pragma unroll
        for (int tm = 0; tm < 2; ++tm)
            #pragma unroll
            for (int tn = 0; tn < 4; ++tn)
                #pragma unroll
                for (int reg = 0; reg < 4; ++reg) {
                    float v = acc[tm][tn][reg];
                    int slot = tm * 4 + reg;
                    int col  = c0 + tn * 16 + l15;
                    if (v > mx[slot]) { mx[slot] = v; mi[slot] = col; }
                }
    }

    #pragma unroll
    for (int slot = 0; slot < 8; ++slot) {
        float v  = mx[slot];
        int  idx = mi[slot];
        #pragma unroll
        for (int off = 1; off < 16; off <<= 1) {
            float ov = __shfl_xor(v, off, 64);
            int   oi = __shfl_xor(idx, off, 64);
            if (ov > v) { v = ov; idx = oi; }
        }
        if (l15 == 0) {
            int rowl = wm * 32 + (slot >> 2) * 16 + q * 4 + (slot & 3);
            redv[rowl][wn] = v;
            redi[rowl][wn] = idx;
        }
    }
    __syncthreads();
    if (tid < 64) {
        int r = r0 + tid;
        if (r < SSUP) {
            float v0 = redv[tid][0], v1 = redv[tid][1];
            top_idx[r] = (v1 > v0) ? redi[tid][1] : redi[tid][0];
        }
    }
}

// ---------------- histogram of top_idx (fallback path) ----------------
__global__ void k_hist(const int* __restrict__ top_idx, int* __restrict__ hist) {
    __shared__ int lh[CB];
    for (int i = threadIdx.x; i < CB; i += blockDim.x) lh[i] = 0;
    __syncthreads();
    for (int i = blockIdx.x * blockDim.x + threadIdx.x; i < SSUP; i += gridDim.x * blockDim.x)
        atomicAdd(&lh[top_idx[i]], 1);
    __syncthreads();
    for (int i = threadIdx.x; i < CB; i += blockDim.x) {
        int v = lh[i];
        if (v) atomicAdd(&hist[i], v);
    }
}

// ---------------- weighted codebook sum (proto_code * S) ----------------
__global__ void k_proto_code(const float* __restrict__ cb, const int* __restrict__ hist,
                             float* __restrict__ pcSum) {
    const int d  = threadIdx.x;          // 512 threads
    const int c0 = blockIdx.x * 64;
    float acc = 0.f;
    for (int c = c0; c < c0 + 64; ++c) {
        float w = (float)hist[c];
        if (w != 0.f) acc += w * cb[(size_t)c * DIM + d];
    }
    atomicAdd(&pcSum[d], acc);
}

// ---------------- query scores ----------------
__global__ void k_query(const float* __restrict__ X, const float* __restrict__ protoSum,
                        const float* __restrict__ pcSum, float* __restrict__ out) {
    const int lane   = threadIdx.x & 63;
    const int waveId = (blockIdx.x * blockDim.x + threadIdx.x) >> 6;
    const int nwaves = (gridDim.x * blockDim.x) >> 6;
    const float invS = 1.0f / (float)SSUP;

    for (int r = waveId; r < NQ; r += nwaves) {
        const float* xr = X + (size_t)(SSUP + r) * DIM;
        float s1 = 0.f, s2 = 0.f;
        #pragma unroll
        for (int i = 0; i < 2; ++i) {
            int dd = lane * 4 + i * 256;
            float4 xq = *(const float4*)(xr + dd);
            float4 p  = *(const float4*)(protoSum + dd);
            float4 pc = *(const float4*)(pcSum + dd);
            float d0, d1, d2, d3;
            d0 = xq.x - p.x * invS; d1 = xq.y - p.y * invS;
            d2 = xq.z - p.z * invS; d3 = xq.w - p.w * invS;
            s1 += d0 * d0 + d1 * d1 + d2 * d2 + d3 * d3;
            d0 = xq.x - pc.x * invS; d1 = xq.y - pc.y * invS;
            d2 = xq.z - pc.z * invS; d3 = xq.w - pc.w * invS;
            s2 += d0 * d0 + d1 * d1 + d2 * d2 + d3 * d3;
        }
        #pragma unroll
        for (int off = 32; off > 0; off >>= 1) {
            s1 += __shfl_xor(s1, off, 64);
            s2 += __shfl_xor(s2, off, 64);
        }
        if (lane == 0)
            out[r] = 0.5f * (sqrtf(s1) + sqrtf(s2));
    }
}

extern "C" void kernel_launch(void* const* d_in, const int* in_sizes, int n_in,
                              void* d_out, int out_size, void* d_ws, size_t ws_size,
                              hipStream_t stream) {
    const float* X  = (const float*)d_in[0];
    const float* cb = (const float*)d_in[1];
    float* out = (float*)d_out;
    char* ws = (char*)d_ws;

    __bf16* cbb = (__bf16*)(ws + OFF_CBBF);

    if (ws_size >= (size_t)WS_NEED) {
        // ---- fast path
        __bf16* Xb       = (__bf16*)(ws + OFF_XB);
        float*  pv       = (float*)(ws + OFF_PV);
        int*    pi       = (int*)(ws + OFF_PI);
        float*  protoSum = (float*)(ws + OFF_PSUM);
        float*  pcSum    = (float*)(ws + OFF_PCSUM);
        int*    hist     = (int*)(ws + OFF_HIST);

        hipMemsetAsync(ws + OFF_PSUM, 0, ZERO_BYTES, stream);

        k_convert<<<(CB * DIM) / 1024, 256, 0, stream>>>(cb, cbb);
        k_conv_psum<<<MPAD / 128, 256, 0, stream>>>(X, Xb, protoSum);

        dim3 grid(NTILES, MTILES);
        k_gemm128<<<grid, 256, 0, stream>>>(Xb, cbb, pv, pi);

        k_reduce_hist<<<(SSUP + 255) / 256, 256, 0, stream>>>(pv, pi, hist);
        k_proto_code<<<CB / 64, 512, 0, stream>>>(cb, hist, pcSum);
        k_query<<<1024, 256, 0, stream>>>(X, protoSum, pcSum, out);
    } else {
        // ---- fallback: round-1 path (needs only ~4.4 MB)
        float*  protoSum = (float*)(ws + F_OFF_PSUM);
        float*  pcSum    = (float*)(ws + F_OFF_PCSUM);
        int*    hist     = (int*)(ws + F_OFF_HIST);
        int*    top_idx  = (int*)(ws + F_OFF_TIDX);

        hipMemsetAsync(ws + F_OFF_PSUM, 0, ZERO_BYTES, stream);

        k_convert<<<(CB * DIM) / 1024, 256, 0, stream>>>(cb, cbb);
        k_proto_sum<<<100, 512, 0, stream>>>(X, protoSum);
        k_gemm_argmax<<<(SSUP + 63) / 64, 256, 0, stream>>>(X, cbb, top_idx);
        k_hist<<<64, 256, 0, stream>>>(top_idx, hist);
        k_proto_code<<<CB / 64, 512, 0, stream>>>(cb, hist, pcSum);
        k_query<<<1024, 256, 0, stream>>>(X, protoSum, pcSum, out);
    }
}

// Round 6
// 626.202 us; speedup vs baseline: 1.2042x; 1.0880x over previous
//
#include <hip/hip_runtime.h>
#include <hip/hip_bf16.h>

// Problem constants (fixed by the reference)
#define NTOT 100000
#define DIM  512
#define CB   4096
#define SSUP 50000
#define NQ   (NTOT - SSUP)

// A-resident GEMM geometry: 64-row M-blocks x 2 N-halves
#define MB64   782            // 782*64 = 50048 rows (48 pad rows are query rows, discarded)
#define MPAD   (MB64 * 64)
#define NHALF  2              // each block covers 16 of 32 col-tiles (2048 cols)
#define NSTEPS 128            // 16 ct x 8 kb per block

typedef __bf16 bf16x8 __attribute__((ext_vector_type(8)));
typedef __bf16 bf16x4 __attribute__((ext_vector_type(4)));
typedef float  f32x4  __attribute__((ext_vector_type(4)));

// ---------------- ws layout, fast path (bytes) — offsets kept from prior rounds ----------------
// cbb @0 (4MB) ; pv @OFF_PV (50048*2*4=400KB) ; pi @OFF_PI ; sums/hist after.
#define OFF_CBBF   0
#define OFF_XB     4194304     /* unused in fast path now */
#define OFF_PV     55443456
#define OFF_PI     61849600
#define OFF_PSUM   68255744
#define OFF_PCSUM  68257792
#define OFF_HIST   68259840
#define OFF_TIDX   68276224
#define WS_NEED    (68276224 + 200000)
#define ZERO_BYTES (2048 + 2048 + 16384)

// ---------------- ws layout, fallback (round-1) ----------------
#define F_OFF_PSUM   4194304
#define F_OFF_PCSUM  4196352
#define F_OFF_HIST   4198400
#define F_OFF_TIDX   4214784

// ---------------- async global->LDS helper ----------------
__device__ __forceinline__ void load_lds16(const void* g, void* l) {
    __builtin_amdgcn_global_load_lds(
        (const __attribute__((address_space(1))) void*)g,
        (__attribute__((address_space(3))) void*)l, 16, 0, 0);
}

#define BARRIER() __builtin_amdgcn_s_barrier()
#define VMC(N)    asm volatile("s_waitcnt vmcnt(" #N ")" ::: "memory")

// ---------------- fp32 -> bf16 convert (codebook) ----------------
__global__ void k_convert(const float* __restrict__ src, __bf16* __restrict__ dst) {
    int i = (blockIdx.x * 256 + threadIdx.x) * 4;
    float4 v = *(const float4*)(src + i);
    bf16x4 o;
    o[0] = (__bf16)v.x; o[1] = (__bf16)v.y; o[2] = (__bf16)v.z; o[3] = (__bf16)v.w;
    *(bf16x4*)(dst + i) = o;
}

// ---------------- support column-sum ----------------
// 391 blocks x 128 rows; thread owns 8 fixed cols; rows >= SSUP excluded.
__global__ __launch_bounds__(256)
void k_psum(const float* __restrict__ X, float* __restrict__ protoSum)
{
    __shared__ float red[4][512];
    const int tid  = threadIdx.x;
    const int c8   = (tid & 63) * 8;
    const int rsub = tid >> 6;
    const size_t rbase = (size_t)blockIdx.x * 128 + rsub;

    float acc[8];
    #pragma unroll
    for (int j = 0; j < 8; ++j) acc[j] = 0.f;

    for (int r = 0; r < 128; r += 4) {
        const size_t row = rbase + r;
        if (row < SSUP) {
            const float* p = X + row * DIM + c8;
            float4 v0 = *(const float4*)p;
            float4 v1 = *(const float4*)(p + 4);
            acc[0] += v0.x; acc[1] += v0.y; acc[2] += v0.z; acc[3] += v0.w;
            acc[4] += v1.x; acc[5] += v1.y; acc[6] += v1.z; acc[7] += v1.w;
        }
    }
    #pragma unroll
    for (int j = 0; j < 8; ++j) red[rsub][c8 + j] = acc[j];
    __syncthreads();
    if (rsub == 0) {
        #pragma unroll
        for (int j = 0; j < 8; ++j)
            atomicAdd(&protoSum[c8 + j],
                      red[0][c8 + j] + red[1][c8 + j] + red[2][c8 + j] + red[3][c8 + j]);
    }
}

// ---------------- A-resident GEMM + per-ct fused argmax ----------------
// Block: 256 thr = 4 waves (2M x 2N). 64 A-rows live in regs (bf16, from fp32 X).
// B streamed: steps (ct,kb): 128 cols x 64 K = 16KB per step, rotating 3-buffer,
// staged 2 steps ahead via global_load_lds (4 loads/thread/step), vmcnt(4),
// ONE barrier per step. T2 XOR swizzle (chunk ^= row&7) on source and read,
// identical to the refcheck'd round-3/4 scheme. Per-ct argmax in registers
// (fallback kernel's verified mx/mi pattern); 2 partials/row written.
__global__ __launch_bounds__(256, 2)
void k_gemm_areg(const float* __restrict__ X, const __bf16* __restrict__ cbb,
                 float* __restrict__ pv, int* __restrict__ pi)
{
    __shared__ __align__(16) char lds[49152];
    __shared__ float sv[64][2];
    __shared__ int   si[64][2];

    const int tid  = threadIdx.x;
    const int lane = tid & 63;
    const int wid  = tid >> 6;            // 0..3
    const int wm   = wid >> 1;            // 0..1 (32-row half)
    const int wn   = wid & 1;             // 0..1 (64-col half)
    const int l15  = lane & 15;
    const int q    = lane >> 4;

    const int bm  = blockIdx.x >> 1;      // 0..781
    const int nh  = blockIdx.x & 1;       // 0..1
    const size_t r0 = (size_t)bm * 64;
    const int ct0 = nh * 16;

    // ---- A: 64 rows x 512 cols into registers (verified fallback layout)
    bf16x8 aflat[2][16];
    #pragma unroll
    for (int tm = 0; tm < 2; ++tm) {
        const size_t r = r0 + wm * 32 + tm * 16 + l15;
        const float* xr = X + r * DIM + q * 8;
        #pragma unroll
        for (int kt = 0; kt < 16; ++kt) {
            float4 v0 = *(const float4*)(xr + kt * 32);
            float4 v1 = *(const float4*)(xr + kt * 32 + 4);
            bf16x8 f;
            f[0] = (__bf16)v0.x; f[1] = (__bf16)v0.y; f[2] = (__bf16)v0.z; f[3] = (__bf16)v0.w;
            f[4] = (__bf16)v1.x; f[5] = (__bf16)v1.y; f[6] = (__bf16)v1.z; f[7] = (__bf16)v1.w;
            aflat[tm][kt] = f;
        }
    }

    // ---- staging precompute: thread stages 4 x 16B chunks per step.
    // chunk ck = i*256+tid -> row = ck>>3 (0..127), swz chunk sc = (ck&7)^(row&7).
    // row&7 == (tid>>3)&7 for all i (i*32 ≡ 0 mod 8), so sc is i-invariant.
    const int sc   = (tid & 7) ^ ((tid >> 3) & 7);
    const int pre0 = (tid >> 3) * DIM + sc * 8;     // element offset, + i*32*DIM per i
    // LDS dest: buf + tid*16 + i*4096 (wave-uniform base + lane-linear 16B)

    auto STAGE = [&](char* buf, int sp) {
        const int c0s = (ct0 + (sp >> 3)) * 128;
        const __bf16* base = cbb + (size_t)c0s * DIM + (sp & 7) * 64 + pre0;
        #pragma unroll
        for (int i = 0; i < 4; ++i)
            load_lds16(base + i * 32 * DIM, buf + tid * 16 + i * 4096);
    };

    // swizzled ds_read byte offsets (row within half = tn*16+l15; row&7 == l15&7)
    const int off0 = l15 * 128 + ((q)     ^ (l15 & 7)) * 16;   // ks=0
    const int off1 = l15 * 128 + ((4 + q) ^ (l15 & 7)) * 16;   // ks=1

    char* p0 = lds;
    char* p1 = lds + 16384;
    char* p2 = lds + 32768;

    // prologue: steps 0,1 in flight (8 wave-loads outstanding)
    STAGE(p0, 0);
    STAGE(p1, 1);

    float mx[8]; int mi[8];
    #pragma unroll
    for (int i = 0; i < 8; ++i) { mx[i] = -3.0e38f; mi[i] = 0; }

    int s = 0;
    #pragma unroll 1
    for (int ct = 0; ct < 16; ++ct) {
        f32x4 acc[2][4];
        #pragma unroll
        for (int i = 0; i < 2; ++i)
            #pragma unroll
            for (int j = 0; j < 4; ++j)
                acc[i][j] = (f32x4){0.f, 0.f, 0.f, 0.f};

        #pragma unroll
        for (int kb = 0; kb < 8; ++kb) {
            // ledger: enter with {s:4, s+1:4} outstanding; VMC(4) retires step-s's 4
            // (vmcnt retires in issue order); barrier makes step-s data visible to
            // all waves. Steps >=126 stage a clamped dummy to keep ledger uniform.
            VMC(4);
            BARRIER();
            {
                int sp = s + 2; if (sp > NSTEPS - 1) sp = NSTEPS - 1;
                STAGE(p2, sp);   // safe: p2 last read 1 barrier ago, write lands post-issue
            }
            // compute step s from p0 (A from regs, B fresh ds_reads)
            const char* bp = p0 + wn * 8192;
            bf16x8 b[4][2];
            #pragma unroll
            for (int tn = 0; tn < 4; ++tn) {
                b[tn][0] = *(const bf16x8*)(bp + tn * 2048 + off0);
                b[tn][1] = *(const bf16x8*)(bp + tn * 2048 + off1);
            }
            __builtin_amdgcn_s_setprio(1);
            #pragma unroll
            for (int tm = 0; tm < 2; ++tm)
                #pragma unroll
                for (int tn = 0; tn < 4; ++tn)
                    #pragma unroll
                    for (int ks = 0; ks < 2; ++ks)
                        acc[tm][tn] = __builtin_amdgcn_mfma_f32_16x16x32_bf16(
                            aflat[tm][2 * kb + ks], b[tn][ks], acc[tm][tn], 0, 0, 0);
            __builtin_amdgcn_s_setprio(0);
            // rotate buffers
            char* t = p0; p0 = p1; p1 = p2; p2 = t;
            ++s;
        }

        // per-ct argmax update (full-K dots complete).
        // C/D: col = (ct0+ct)*128 + wn*64 + tn*16 + l15 ; row = wm*32 + tm*16 + q*4 + reg
        const int cbase = (ct0 + ct) * 128 + wn * 64;
        #pragma unroll
        for (int tm = 0; tm < 2; ++tm)
            #pragma unroll
            for (int tn = 0; tn < 4; ++tn)
                #pragma unroll
                for (int reg = 0; reg < 4; ++reg) {
                    float v = acc[tm][tn][reg];
                    int slot = tm * 4 + reg;
                    int col  = cbase + tn * 16 + l15;
                    if (v > mx[slot]) { mx[slot] = v; mi[slot] = col; }
                }
    }
    VMC(0);   // hygiene: drain dangling dummy stages

    // ---- cross-lane reduce within 16-lane col groups, then combine wn halves
    #pragma unroll
    for (int slot = 0; slot < 8; ++slot) {
        float v  = mx[slot];
        int  idx = mi[slot];
        #pragma unroll
        for (int off = 1; off < 16; off <<= 1) {
            float ov = __shfl_xor(v, off, 64);
            int   oi = __shfl_xor(idx, off, 64);
            if (ov > v) { v = ov; idx = oi; }
        }
        if (l15 == 0) {
            int rowl = wm * 32 + (slot >> 2) * 16 + q * 4 + (slot & 3);
            sv[rowl][wn] = v;
            si[rowl][wn] = idx;
        }
    }
    __syncthreads();
    if (tid < 64) {
        float v0 = sv[tid][0], v1 = sv[tid][1];
        size_t r = r0 + tid;
        pv[r * 2 + nh] = fmaxf(v0, v1);
        pi[r * 2 + nh] = (v1 > v0) ? si[tid][1] : si[tid][0];
    }
}

// ---------------- phase-2: reduce 2 partials per row + histogram ----------------
__global__ __launch_bounds__(256)
void k_reduce_hist2(const float* __restrict__ pv, const int* __restrict__ pi,
                    int* __restrict__ hist) {
    __shared__ int lh[CB];
    const int tid = threadIdx.x;
    for (int i = tid; i < CB; i += 256) lh[i] = 0;
    __syncthreads();
    const int r = blockIdx.x * 256 + tid;
    if (r < SSUP) {
        float v0 = pv[(size_t)r * 2];
        float v1 = pv[(size_t)r * 2 + 1];
        int idx = (v1 > v0) ? pi[(size_t)r * 2 + 1] : pi[(size_t)r * 2];
        atomicAdd(&lh[idx], 1);
    }
    __syncthreads();
    for (int i = tid; i < CB; i += 256) {
        int v = lh[i];
        if (v) atomicAdd(&hist[i], v);
    }
}

// ---------------- column sums of support (fallback path) ----------------
__global__ void k_proto_sum(const float* __restrict__ X, float* __restrict__ protoSum) {
    const int d = threadIdx.x;              // 512 threads
    const int r0 = blockIdx.x * 500;        // 100 blocks x 500 rows
    float acc = 0.f;
    for (int r = r0; r < r0 + 500; ++r)
        acc += X[(size_t)r * DIM + d];
    atomicAdd(&protoSum[d], acc);
}

// ---------------- fallback GEMM (round-1, known-correct) ----------------
__global__ __launch_bounds__(256, 2)
void k_gemm_argmax(const float* __restrict__ X, const __bf16* __restrict__ cbb,
                   int* __restrict__ top_idx)
{
    __shared__ float redv[64][2];
    __shared__ int   redi[64][2];

    const int tid  = threadIdx.x;
    const int wave = tid >> 6;
    const int lane = tid & 63;
    const int wm   = wave >> 1;
    const int wn   = wave & 1;
    const int l15  = lane & 15;
    const int q    = lane >> 4;
    const int r0   = blockIdx.x * 64;

    bf16x8 aflat[2][16];
    #pragma unroll
    for (int tm = 0; tm < 2; ++tm) {
        const int r = r0 + wm * 32 + tm * 16 + l15;
        const bool valid = (r < SSUP);
        const float* xr = X + (size_t)r * DIM + q * 8;
        #pragma unroll
        for (int kt = 0; kt < 16; ++kt) {
            float4 v0, v1;
            if (valid) {
                v0 = *(const float4*)(xr + kt * 32);
                v1 = *(const float4*)(xr + kt * 32 + 4);
            } else {
                v0 = make_float4(0.f, 0.f, 0.f, 0.f);
                v1 = v0;
            }
            bf16x8 f;
            f[0] = (__bf16)v0.x; f[1] = (__bf16)v0.y; f[2] = (__bf16)v0.z; f[3] = (__bf16)v0.w;
            f[4] = (__bf16)v1.x; f[5] = (__bf16)v1.y; f[6] = (__bf16)v1.z; f[7] = (__bf16)v1.w;
            aflat[tm][kt] = f;
        }
    }

    float mx[8];
    int   mi[8];
    #pragma unroll
    for (int i = 0; i < 8; ++i) { mx[i] = -3.0e38f; mi[i] = 0; }
    const f32x4 zero4 = {0.f, 0.f, 0.f, 0.f};

    for (int ct = 0; ct < 32; ++ct) {
        const int c0 = ct * 128 + wn * 64;
        const __bf16* bptr[4];
        #pragma unroll
        for (int tn = 0; tn < 4; ++tn)
            bptr[tn] = cbb + (size_t)(c0 + tn * 16 + l15) * DIM + q * 8;

        f32x4 acc[2][4];
        #pragma unroll
        for (int i = 0; i < 2; ++i)
            #pragma unroll
            for (int j = 0; j < 4; ++j)
                acc[i][j] = zero4;

        #pragma unroll
        for (int kt = 0; kt < 16; ++kt) {
            bf16x8 b[4];
            #pragma unroll
            for (int tn = 0; tn < 4; ++tn)
                b[tn] = *(const bf16x8*)(bptr[tn] + kt * 32);
            #pragma unroll
            for (int tm = 0; tm < 2; ++tm)
                #pragma unroll
                for (int tn = 0; tn < 4; ++tn)
                    acc[tm][tn] = __builtin_amdgcn_mfma_f32_16x16x32_bf16(
                        aflat[tm][kt], b[tn], acc[tm][tn], 0, 0, 0);
        }
        #pragma unroll
        for (int tm = 0; tm < 2; ++tm)
            #pragma unroll
            for (int tn = 0; tn < 4; ++tn)
                #pragma unroll
                for (int reg = 0; reg < 4; ++reg) {
                    float v = acc[tm][tn][reg];
                    int slot = tm * 4 + reg;
                    int col  = c0 + tn * 16 + l15;
                    if (v > mx[slot]) { mx[slot] = v; mi[slot] = col; }
                }
    }

    #pragma unroll
    for (int slot = 0; slot < 8; ++slot) {
        float v  = mx[slot];
        int  idx = mi[slot];
        #pragma unroll
        for (int off = 1; off < 16; off <<= 1) {
            float ov = __shfl_xor(v, off, 64);
            int   oi = __shfl_xor(idx, off, 64);
            if (ov > v) { v = ov; idx = oi; }
        }
        if (l15 == 0) {
            int rowl = wm * 32 + (slot >> 2) * 16 + q * 4 + (slot & 3);
            redv[rowl][wn] = v;
            redi[rowl][wn] = idx;
        }
    }
    __syncthreads();
    if (tid < 64) {
        int r = r0 + tid;
        if (r < SSUP) {
            float v0 = redv[tid][0], v1 = redv[tid][1];
            top_idx[r] = (v1 > v0) ? redi[tid][1] : redi[tid][0];
        }
    }
}

// ---------------- histogram of top_idx (fallback path) ----------------
__global__ void k_hist(const int* __restrict__ top_idx, int* __restrict__ hist) {
    __shared__ int lh[CB];
    for (int i = threadIdx.x; i < CB; i += blockDim.x) lh[i] = 0;
    __syncthreads();
    for (int i = blockIdx.x * blockDim.x + threadIdx.x; i < SSUP; i += gridDim.x * blockDim.x)
        atomicAdd(&lh[top_idx[i]], 1);
    __syncthreads();
    for (int i = threadIdx.x; i < CB; i += blockDim.x) {
        int v = lh[i];
        if (v) atomicAdd(&hist[i], v);
    }
}

// ---------------- weighted codebook sum (proto_code * S) ----------------
__global__ void k_proto_code(const float* __restrict__ cb, const int* __restrict__ hist,
                             float* __restrict__ pcSum) {
    const int d  = threadIdx.x;          // 512 threads
    const int c0 = blockIdx.x * 64;
    float acc = 0.f;
    for (int c = c0; c < c0 + 64; ++c) {
        float w = (float)hist[c];
        if (w != 0.f) acc += w * cb[(size_t)c * DIM + d];
    }
    atomicAdd(&pcSum[d], acc);
}

// ---------------- query scores ----------------
__global__ void k_query(const float* __restrict__ X, const float* __restrict__ protoSum,
                        const float* __restrict__ pcSum, float* __restrict__ out) {
    const int lane   = threadIdx.x & 63;
    const int waveId = (blockIdx.x * blockDim.x + threadIdx.x) >> 6;
    const int nwaves = (gridDim.x * blockDim.x) >> 6;
    const float invS = 1.0f / (float)SSUP;

    for (int r = waveId; r < NQ; r += nwaves) {
        const float* xr = X + (size_t)(SSUP + r) * DIM;
        float s1 = 0.f, s2 = 0.f;
        #pragma unroll
        for (int i = 0; i < 2; ++i) {
            int dd = lane * 4 + i * 256;
            float4 xq = *(const float4*)(xr + dd);
            float4 p  = *(const float4*)(protoSum + dd);
            float4 pc = *(const float4*)(pcSum + dd);
            float d0, d1, d2, d3;
            d0 = xq.x - p.x * invS; d1 = xq.y - p.y * invS;
            d2 = xq.z - p.z * invS; d3 = xq.w - p.w * invS;
            s1 += d0 * d0 + d1 * d1 + d2 * d2 + d3 * d3;
            d0 = xq.x - pc.x * invS; d1 = xq.y - pc.y * invS;
            d2 = xq.z - pc.z * invS; d3 = xq.w - pc.w * invS;
            s2 += d0 * d0 + d1 * d1 + d2 * d2 + d3 * d3;
        }
        #pragma unroll
        for (int off = 32; off > 0; off >>= 1) {
            s1 += __shfl_xor(s1, off, 64);
            s2 += __shfl_xor(s2, off, 64);
        }
        if (lane == 0)
            out[r] = 0.5f * (sqrtf(s1) + sqrtf(s2));
    }
}

extern "C" void kernel_launch(void* const* d_in, const int* in_sizes, int n_in,
                              void* d_out, int out_size, void* d_ws, size_t ws_size,
                              hipStream_t stream) {
    const float* X  = (const float*)d_in[0];
    const float* cb = (const float*)d_in[1];
    float* out = (float*)d_out;
    char* ws = (char*)d_ws;

    __bf16* cbb = (__bf16*)(ws + OFF_CBBF);

    if (ws_size >= (size_t)WS_NEED) {
        // ---- fast path: A-resident-in-registers GEMM, B streamed via LDS 3-buffer
        float*  pv       = (float*)(ws + OFF_PV);
        int*    pi       = (int*)(ws + OFF_PI);
        float*  protoSum = (float*)(ws + OFF_PSUM);
        float*  pcSum    = (float*)(ws + OFF_PCSUM);
        int*    hist     = (int*)(ws + OFF_HIST);

        hipMemsetAsync(ws + OFF_PSUM, 0, ZERO_BYTES, stream);

        k_convert<<<(CB * DIM) / 1024, 256, 0, stream>>>(cb, cbb);
        k_psum<<<MPAD / 128, 256, 0, stream>>>(X, protoSum);

        k_gemm_areg<<<MB64 * NHALF, 256, 0, stream>>>(X, cbb, pv, pi);

        k_reduce_hist2<<<(SSUP + 255) / 256, 256, 0, stream>>>(pv, pi, hist);
        k_proto_code<<<CB / 64, 512, 0, stream>>>(cb, hist, pcSum);
        k_query<<<1024, 256, 0, stream>>>(X, protoSum, pcSum, out);
    } else {
        // ---- fallback: round-1 path (needs only ~4.4 MB)
        float*  protoSum = (float*)(ws + F_OFF_PSUM);
        float*  pcSum    = (float*)(ws + F_OFF_PCSUM);
        int*    hist     = (int*)(ws + F_OFF_HIST);
        int*    top_idx  = (int*)(ws + F_OFF_TIDX);

        hipMemsetAsync(ws + F_OFF_PSUM, 0, ZERO_BYTES, stream);

        k_convert<<<(CB * DIM) / 1024, 256, 0, stream>>>(cb, cbb);
        k_proto_sum<<<100, 512, 0, stream>>>(X, protoSum);
        k_gemm_argmax<<<(SSUP + 63) / 64, 256, 0, stream>>>(X, cbb, top_idx);
        k_hist<<<64, 256, 0, stream>>>(top_idx, hist);
        k_proto_code<<<CB / 64, 512, 0, stream>>>(cb, hist, pcSum);
        k_query<<<1024, 256, 0, stream>>>(X, protoSum, pcSum, out);
    }
}